// Round 10
// baseline (173.905 us; speedup 1.0000x reference)
//
#include <hip/hip_runtime.h>
#include <hip/hip_bf16.h>

using bf16 = __hip_bfloat16;
typedef __attribute__((ext_vector_type(8))) short frag8;   // 8 bf16 (4 VGPRs)
typedef __attribute__((ext_vector_type(8))) short short8v;
typedef __attribute__((ext_vector_type(4))) float f32x4;   // 4 fp32 acc

constexpr int   H_   = 1024;               // N_EMBD
constexpr int   B_   = 8;                  // BATCH
constexpr int   T_   = 2048;
constexpr int   K_   = H_;
constexpr int   N_   = H_;
constexpr long  M_   = (long)B_ * T_;      // 16384
constexpr int   SEG  = 64;                 // segments per sequence
constexpr int   TSEG = T_ / SEG;           // 32
constexpr int   NCH  = B_ * H_;            // 8192 channels
constexpr int   NVC  = NCH / 4;            // 2048 vec4-channels

__device__ __forceinline__ unsigned short f2bf(float f) {
  bf16 b = __float2bfloat16(f);
  return *reinterpret_cast<unsigned short*>(&b);
}
__device__ __forceinline__ float bf2f(unsigned short u) {
  unsigned v = (unsigned)u << 16;
  return *reinterpret_cast<float*>(&v);
}

__device__ __forceinline__ float4 fma4(float4 h, float4 a, float4 v) {
  float4 r;
  r.x = fmaf(h.x, a.x, v.x);
  r.y = fmaf(h.y, a.y, v.y);
  r.z = fmaf(h.z, a.z, v.z);
  r.w = fmaf(h.w, a.w, v.w);
  return r;
}

// ---------------- B fp32 -> bf16 + fused sigmoid (R10: x-path moved into GEMM) ----------------
__global__ __launch_bounds__(256) void k_convert(const float* __restrict__ Bm,
                                                 const float* __restrict__ raw,
                                                 unsigned short* __restrict__ Bb,
                                                 float* __restrict__ a_sig) {
  const long NB8 = ((long)N_ * K_) / 8;       // 131072
  long t = (long)blockIdx.x * 256 + threadIdx.x;
  if (t < NB8) {
    long i = t * 8;
    float4 v0 = *reinterpret_cast<const float4*>(Bm + i);
    float4 v1 = *reinterpret_cast<const float4*>(Bm + i + 4);
    short8v o;
    o[0] = (short)f2bf(v0.x); o[1] = (short)f2bf(v0.y);
    o[2] = (short)f2bf(v0.z); o[3] = (short)f2bf(v0.w);
    o[4] = (short)f2bf(v1.x); o[5] = (short)f2bf(v1.y);
    o[6] = (short)f2bf(v1.z); o[7] = (short)f2bf(v1.w);
    *reinterpret_cast<short8v*>(Bb + i) = o;
    return;
  }
  long q = t - NB8;
  if (q >= H_ / 4) return;
  float4 v = *reinterpret_cast<const float4*>(raw + q * 4);
  float4 o;
  o.x = 1.0f / (1.0f + expf(-v.x));
  o.y = 1.0f / (1.0f + expf(-v.y));
  o.z = 1.0f / (1.0f + expf(-v.z));
  o.w = 1.0f / (1.0f + expf(-v.w));
  *reinterpret_cast<float4*>(a_sig + q * 4) = o;
}

// ---------------- bf16 GEMM: 256x256 tile, BK=64, 8-wave, 8-phase counted-vmcnt pipeline ----------------
// R4: T2 XOR swizzle (conflicts 0). R5: one barrier/phase. R8: fused seg_ends.
// R9: bf16 u-store. R10: A staged from fp32 x IN-KERNEL (reg-stage: global fp32
// loads -> cvt -> ds_write), removing the x-convert pass (-64 MB HBM).
// vmcnt ledger (A = 4 plain loads/issue, B = 2 gload_lds/issue; per-wave):
//  p1 I:A1 | p2 I:B2, VMW(6) [drain A8prev], WR dbuf1h0, LGKM0 | p3 I:B3, VMW(4)
//  [drain A1], WR dbuf1h1, LGKM0 | p4 I:A4, VMW(4) [publish B2,B3] | p5 I:A5 |
//  p6 I:B6, VMW(6) [drain A4], WR dbuf0h0, LGKM0 | p7 I:B7, VMW(4) [drain A5],
//  WR dbuf0h1, LGKM0 | p8 I:A8, VMW(4) [publish B6,B7].
// LDS write->read >=3 barriers; write-after-last-read >=4 barriers (all buffers).
// LGKM0 before BARR in write phases makes ds_write cross-wave visible.
#define MEMBAR asm volatile("" ::: "memory")
#define BARR do { MEMBAR; __builtin_amdgcn_s_barrier(); MEMBAR; } while (0)
#define VMW(n) asm volatile("s_waitcnt vmcnt(" #n ")" ::: "memory")
#define LGKM0 asm volatile("s_waitcnt lgkmcnt(0)" ::: "memory")
#define GLDS(SRC, DST) __builtin_amdgcn_global_load_lds( \
    (const __attribute__((address_space(1))) void*)(SRC), \
    (__attribute__((address_space(3))) void*)(DST), 16, 0, 0)

struct ARegs { float4 f0, f1, f2, f3; };

__global__ __launch_bounds__(512, 2) void k_gemm(const float* __restrict__ X,
                                                 const unsigned short* __restrict__ Bb,
                                                 unsigned short* __restrict__ UB,
                                                 const float* __restrict__ a_sig,
                                                 float* __restrict__ E) {
  __shared__ __align__(16) unsigned short lA[32768];   // 64 KiB
  __shared__ __align__(16) unsigned short lB[32768];   // 64 KiB
  const int tid  = threadIdx.x;
  const int wid  = tid >> 6, lane = tid & 63;
  const int wr   = wid >> 2, wc = wid & 3;             // 2x4 wave grid
  const int quad = lane >> 4, l16 = lane & 15;
  const int sx   = l16 & 7;                            // read-side swizzle key
  const int bh   = wc >> 1, br = (wc & 1) * 64;        // B half / row base for this wave
  const int bid  = blockIdx.x;
  const int wgid = (bid & 7) * 32 + (bid >> 3);        // XCD-chunked swizzle (256%8==0, bijective)
  const long m0 = (long)(wgid >> 2) * 256;
  const long n0 = (long)(wgid & 3) * 256;
  // stage-side: inverse-swizzled global source (same XOR involution)
  const int sgran = (tid & 7) ^ ((tid >> 3) & 7);
  const float*          gX = X  + (m0 + (tid >> 3)) * K_ + sgran * 8;   // fp32 A source
  const unsigned short* gB = Bb + (n0 + (tid >> 3)) * K_ + sgran * 8;
  unsigned short* sAw = lA + wid * 512;                // wave-uniform LDS dest slice
  unsigned short* sBw = lB + wid * 512;

#define LD_A(dst, hf, t) do { \
    const float* p0_ = gX + ((hf) * 128) * K_ + (t) * 64; \
    const float* p1_ = gX + ((hf) * 128 + 64) * K_ + (t) * 64; \
    dst.f0 = *reinterpret_cast<const float4*>(p0_); \
    dst.f1 = *reinterpret_cast<const float4*>(p0_ + 4); \
    dst.f2 = *reinterpret_cast<const float4*>(p1_); \
    dst.f3 = *reinterpret_cast<const float4*>(p1_ + 4); } while (0)
#define WR_A(d, hf, src) do { \
    unsigned short* wp_ = sAw + (d) * 16384 + (hf) * 8192 + lane * 8; \
    short8v o0_, o1_; \
    o0_[0] = (short)f2bf(src.f0.x); o0_[1] = (short)f2bf(src.f0.y); \
    o0_[2] = (short)f2bf(src.f0.z); o0_[3] = (short)f2bf(src.f0.w); \
    o0_[4] = (short)f2bf(src.f1.x); o0_[5] = (short)f2bf(src.f1.y); \
    o0_[6] = (short)f2bf(src.f1.z); o0_[7] = (short)f2bf(src.f1.w); \
    o1_[0] = (short)f2bf(src.f2.x); o1_[1] = (short)f2bf(src.f2.y); \
    o1_[2] = (short)f2bf(src.f2.z); o1_[3] = (short)f2bf(src.f2.w); \
    o1_[4] = (short)f2bf(src.f3.x); o1_[5] = (short)f2bf(src.f3.y); \
    o1_[6] = (short)f2bf(src.f3.z); o1_[7] = (short)f2bf(src.f3.w); \
    *reinterpret_cast<short8v*>(wp_) = o0_; \
    *reinterpret_cast<short8v*>(wp_ + 4096) = o1_; } while (0)
#define STG_B(d, hf, t) do { \
    GLDS(gB + ((hf) * 128) * K_ + (t) * 64,      sBw + (d) * 16384 + (hf) * 8192); \
    GLDS(gB + ((hf) * 128 + 64) * K_ + (t) * 64, sBw + (d) * 16384 + (hf) * 8192 + 4096); } while (0)

  f32x4 acc[8][4];
  #pragma unroll
  for (int i = 0; i < 8; i++)
    #pragma unroll
    for (int j = 0; j < 4; j++) acc[i][j] = f32x4{0.f, 0.f, 0.f, 0.f};

  frag8 aR[4][2];        // current ih-half A frags: [ii][ks]
  frag8 bR[2][2][2];     // both jh halves live:    [jh][jj][ks]
  ARegs aP, aQ, aRg, aS; // in-flight A stagings

#define RD_A(d, ih) do { _Pragma("unroll") \
    for (int ii = 0; ii < 4; ii++) { \
      const unsigned short* rp = lA + (d) * 16384 + wr * 8192 + (((ih) * 4 + ii) * 16 + l16) * 64; \
      aR[ii][0] = *(const frag8*)(rp + (quad ^ sx) * 8); \
      aR[ii][1] = *(const frag8*)(rp + ((quad + 4) ^ sx) * 8); } } while (0)
#define RD_B(d, jh) do { _Pragma("unroll") \
    for (int jj = 0; jj < 2; jj++) { \
      const unsigned short* rp = lB + (d) * 16384 + bh * 8192 + (br + ((jh) * 2 + jj) * 16 + l16) * 64; \
      bR[jh][jj][0] = *(const frag8*)(rp + (quad ^ sx) * 8); \
      bR[jh][jj][1] = *(const frag8*)(rp + ((quad + 4) ^ sx) * 8); } } while (0)
#define MMQ(ih, jh) do { __builtin_amdgcn_s_setprio(1); _Pragma("unroll") \
    for (int ii = 0; ii < 4; ii++) { _Pragma("unroll") \
      for (int jj = 0; jj < 2; jj++) { \
        acc[(ih)*4+ii][(jh)*2+jj] = __builtin_amdgcn_mfma_f32_16x16x32_bf16(aR[ii][0], bR[jh][jj][0], acc[(ih)*4+ii][(jh)*2+jj], 0, 0, 0); \
        acc[(ih)*4+ii][(jh)*2+jj] = __builtin_amdgcn_mfma_f32_16x16x32_bf16(aR[ii][1], bR[jh][jj][1], acc[(ih)*4+ii][(jh)*2+jj], 0, 0, 0); } } \
    __builtin_amdgcn_s_setprio(0); } while (0)

  // prologue: A t0h0,t0h1 (8 loads) + B t0 (4 glds) + A t1h0 (4 loads)
  LD_A(aQ, 0, 0); LD_A(aRg, 1, 0);
  STG_B(0, 0, 0); STG_B(0, 1, 0);
  LD_A(aS, 0, 1);
  VMW(8);                       // drain aQ, aRg loads (leave B(4)+aS(4))
  WR_A(0, 0, aQ); WR_A(0, 1, aRg);
  LGKM0;
  VMW(4);                       // publish B (leave aS)
  BARR;

  for (int it = 0; it < 7; ++it) {
    const int to = 2 * it + 1, te2 = 2 * it + 2, to2 = 2 * it + 3;
    RD_A(0, 0); RD_B(0, 0); LD_A(aP, 1, to);                              BARR; MMQ(0, 0);  // p1
    RD_B(0, 1); STG_B(1, 0, to);  VMW(6); WR_A(1, 0, aS);  LGKM0;         BARR; MMQ(0, 1);  // p2
    RD_A(0, 1); STG_B(1, 1, to);  VMW(4); WR_A(1, 1, aP);  LGKM0;         BARR; MMQ(1, 1);  // p3
                LD_A(aQ, 0, te2); VMW(4);                                 BARR; MMQ(1, 0);  // p4
    RD_A(1, 0); RD_B(1, 0); LD_A(aRg, 1, te2);                            BARR; MMQ(0, 0);  // p5
    RD_B(1, 1); STG_B(0, 0, te2); VMW(6); WR_A(0, 0, aQ);  LGKM0;         BARR; MMQ(0, 1);  // p6
    RD_A(1, 1); STG_B(0, 1, te2); VMW(4); WR_A(0, 1, aRg); LGKM0;         BARR; MMQ(1, 1);  // p7
                LD_A(aS, 0, to2); VMW(4);                                 BARR; MMQ(1, 0);  // p8
  }
  // peeled final iteration (tiles 14 = dbuf0, 15 = dbuf1)
  RD_A(0, 0); RD_B(0, 0); LD_A(aP, 1, 15);                                BARR; MMQ(0, 0);
  RD_B(0, 1); STG_B(1, 0, 15); VMW(6); WR_A(1, 0, aS); LGKM0;             BARR; MMQ(0, 1);
  RD_A(0, 1); STG_B(1, 1, 15); VMW(4); WR_A(1, 1, aP); LGKM0;             BARR; MMQ(1, 1);
                               VMW(0);                                    BARR; MMQ(1, 0);
  RD_A(1, 0); RD_B(1, 0);                                                 BARR; MMQ(0, 0);
  RD_B(1, 1);                                                             BARR; MMQ(0, 1);
  RD_A(1, 1);                                                             BARR; MMQ(1, 1);
  MMQ(1, 0);

  // epilogue 1 (R9-verified): u-store bf16. C/D layout col=l16, row=quad*4+r.
  #pragma unroll
  for (int i = 0; i < 8; i++)
    #pragma unroll
    for (int j = 0; j < 4; j++) {
      const long r0 = m0 + wr * 128 + i * 16 + quad * 4;
      const long c0 = n0 + wc * 64 + j * 16 + l16;
      #pragma unroll
      for (int r = 0; r < 4; r++)
        UB[(r0 + r) * N_ + c0] = f2bf(acc[i][j][r]);
    }

  // epilogue 2 (R8-verified): fused seg_ends. tau = 16*(i&1) + 4*quad + r.
  {
    const int bb = (int)(m0 >> 11);           // batch
    const int sB = (int)((m0 & 2047) >> 5);   // first global segment of this tile
    #pragma unroll
    for (int j = 0; j < 4; j++) {
      const int c0 = (int)(n0) + wc * 64 + j * 16 + l16;   // channel h (0..1023)
      const float a  = a_sig[c0];
      const float a2 = a * a, a4 = a2 * a2;
      float p4[8];
      p4[0] = 1.f;
      #pragma unroll
      for (int k = 1; k < 8; k++) p4[k] = p4[k - 1] * a4;
      #pragma unroll
      for (int sp = 0; sp < 4; sp++) {        // segment pair = i>>1
        const f32x4 v = acc[sp * 2][j];       // di = 0 rows
        const f32x4 w = acc[sp * 2 + 1][j];   // di = 1 rows
        float p0 = ((v[0] * a + v[1]) * a + v[2]) * a + v[3];
        float p1 = ((w[0] * a + w[1]) * a + w[2]) * a + w[3];
        float e = p4[7 - quad] * p0 + p4[3 - quad] * p1;   // a^(28-16di-4quad) weights
        e += __shfl_xor(e, 16, 64);
        e += __shfl_xor(e, 32, 64);
        if (quad == 0) {
          const int sg = sB + wr * 4 + sp;    // global segment 0..63
          E[(long)sg * NCH + bb * H_ + c0] = e;
        }
      }
    }
  }
}

// ---------------- scan (R9-verified): reads bf16-u from workspace, writes fp32 y to out ----------------
__global__ __launch_bounds__(256) void k_scan_bf(float* __restrict__ y,
                                                 const unsigned short* __restrict__ ub,
                                                 const float* __restrict__ E,
                                                 const float* __restrict__ h0,
                                                 const float* __restrict__ a_sig) {
  int g = blockIdx.x * 256 + threadIdx.x;
  int vc = g & (NVC - 1);
  int s  = g >> 11;
  int b  = vc >> 8;
  int h4 = (vc & 255) * 4;
  float4 a = *reinterpret_cast<const float4*>(a_sig + h4);
  float4 aL = a;
  #pragma unroll
  for (int i = 0; i < 5; i++) { aL.x *= aL.x; aL.y *= aL.y; aL.z *= aL.z; aL.w *= aL.w; } // a^32
  float4 hs = *reinterpret_cast<const float4*>(h0 + (long)vc * 4);
  int j = 0;
  for (; j + 8 <= s; j += 8) {
    float4 e[8];
    #pragma unroll
    for (int q = 0; q < 8; q++)
      e[q] = *reinterpret_cast<const float4*>(E + (long)(j + q) * NCH + (long)vc * 4);
    #pragma unroll
    for (int q = 0; q < 8; q++)
      hs = fma4(hs, aL, e[q]);
  }
  for (; j < s; ++j) {
    float4 e = *reinterpret_cast<const float4*>(E + (long)j * NCH + (long)vc * 4);
    hs = fma4(hs, aL, e);
  }

  const long row0 = (long)b * T_ + (long)s * TSEG;
  const unsigned short* ubase = ub + row0 * H_ + h4;
  float* ybase = y + row0 * H_ + h4;

  short4 v0[8], v1[8];
  #pragma unroll
  for (int jj = 0; jj < 8; jj++)
    v0[jj] = *reinterpret_cast<const short4*>(ubase + (long)jj * H_);
  #pragma unroll
  for (int t0 = 0; t0 < TSEG; t0 += 8) {
    const bool odd = (t0 >> 3) & 1;
    short4* cur = odd ? v1 : v0;
    short4* nxt = odd ? v0 : v1;
    if (t0 + 8 < TSEG) {
      #pragma unroll
      for (int jj = 0; jj < 8; jj++)
        nxt[jj] = *reinterpret_cast<const short4*>(ubase + (long)(t0 + 8 + jj) * H_);
    }
    #pragma unroll
    for (int jj = 0; jj < 8; jj++) {
      float4 v;
      v.x = bf2f((unsigned short)cur[jj].x);
      v.y = bf2f((unsigned short)cur[jj].y);
      v.z = bf2f((unsigned short)cur[jj].z);
      v.w = bf2f((unsigned short)cur[jj].w);
      hs = fma4(hs, a, v);
      *reinterpret_cast<float4*>(ybase + (long)(t0 + jj) * H_) = hs;
    }
  }
}

extern "C" void kernel_launch(void* const* d_in, const int* in_sizes, int n_in,
                              void* d_out, int out_size, void* d_ws, size_t ws_size,
                              hipStream_t stream) {
  const float* x    = (const float*)d_in[0];   // [8,2048,1024]
  const float* rawa = (const float*)d_in[1];   // [1024]
  const float* Bm   = (const float*)d_in[2];   // [1024,1024]
  const float* h0   = (const float*)d_in[3];   // [8,1024]
  float* y = (float*)d_out;

  // Workspace (offsets unchanged from R9; xb region now unused):
  // [0,32Mi) dead | Bb 2 MiB | a_sig 4 KiB | E 2 MiB | ub 32 MiB
  char* w = (char*)d_ws;
  unsigned short* Bb = (unsigned short*)(w + 33554432);                  // 2 MiB
  float* a_sig = (float*)(w + 33554432 + 2097152);                       // 4 KiB
  float* E     = (float*)(w + 33554432 + 2097152 + 4096);                // 2 MiB
  unsigned short* ub = (unsigned short*)(w + 37752832);                  // 32 MiB

  // convert: NB8 = 131072 vec8 elems -> 512 blocks + 1 sigmoid-tail block
  hipLaunchKernelGGL(k_convert, dim3(513), dim3(256), 0, stream, Bm, rawa, Bb, a_sig);
  hipLaunchKernelGGL(k_gemm, dim3(256), dim3(512), 0, stream, x, Bb, ub, a_sig, E);
  hipLaunchKernelGGL(k_scan_bf, dim3(NVC * SEG / 256), dim3(256), 0, stream, y, ub, E, h0, a_sig);
}